// Round 12
// baseline (87.166 us; speedup 1.0000x reference)
//
#include <hip/hip_runtime.h>
#include <stdint.h>

#define HH 4096
#define WW 4096
#define CC 3
#define NLOOP 1000
#define NBLK 8192    // all blocks copy; first NLOOP also run desc AFTER copying
#define NTHR 256
#define N4 ((CC * HH * WW) / 4)
#define CSTRIDE (NBLK * NTHR)
static_assert(N4 == 6 * CSTRIDE, "copy loop must be exactly 6 iterations");

typedef float vfloat4 __attribute__((ext_vector_type(4)));

struct Desc {
  int psh, psw;
  unsigned long long mask;
  unsigned char src[CC][64];
  unsigned char pad[48];
};
static_assert(sizeof(Desc) == 256, "desc size");

// JAX threefry2x32 (20 rounds), exact port of _threefry2x32_lowering.
__device__ __forceinline__ void tf2x32(uint32_t k0, uint32_t k1,
                                       uint32_t x0, uint32_t x1,
                                       uint32_t& o0, uint32_t& o1) {
  const uint32_t ks2 = k0 ^ k1 ^ 0x1BD11BDAu;
  x0 += k0; x1 += k1;
#define ROTL_(v,r) (((v)<<(r))|((v)>>(32-(r))))
#define RND_(r) { x0 += x1; x1 = ROTL_(x1,(r)); x1 ^= x0; }
  RND_(13) RND_(15) RND_(26) RND_(6)
  x0 += k1; x1 += ks2 + 1u;
  RND_(17) RND_(29) RND_(16) RND_(24)
  x0 += ks2; x1 += k0 + 2u;
  RND_(13) RND_(15) RND_(26) RND_(6)
  x0 += k0; x1 += k1 + 3u;
  RND_(17) RND_(29) RND_(16) RND_(24)
  x0 += k1; x1 += ks2 + 4u;
  RND_(13) RND_(15) RND_(26) RND_(6)
  x0 += ks2; x1 += k0 + 5u;
  o0 = x0; o1 = x1;
#undef RND_
#undef ROTL_
}

// 32-bit random_bits under partitionable threefry: XOR of the two output words.
__device__ __forceinline__ uint32_t rb32(uint32_t k0, uint32_t k1,
                                         uint32_t x0, uint32_t x1) {
  uint32_t o0, o1;
  tf2x32(k0, k1, x0, x1, o0, o1);
  return o0 ^ o1;
}

// Dispatch 1: every block copies its 6 float4 chunks (plain loads AND plain
// stores this round — A/B vs NT stores); blocks [0,NLOOP) then derive their
// window descriptor in the memory-drain tail.
__global__ __launch_bounds__(NTHR) void k_copy_desc(
    const int* __restrict__ seedp, Desc* __restrict__ d, int4* __restrict__ geo,
    const float* __restrict__ in, float* __restrict__ out) {
  const int b = blockIdx.x;
  const int tid = threadIdx.x;

  // ---- copy: exactly 6 strided float4s per thread, starts at cycle 0 ----
  {
    const vfloat4* __restrict__ in4 = (const vfloat4*)in;
    vfloat4* __restrict__ out4 = (vfloat4*)out;
    const int idx = b * NTHR + tid;
    #pragma unroll
    for (int k = 0; k < 6; ++k) {
      const int i = idx + k * CSTRIDE;
      out4[i] = in4[i];
    }
  }

  if (b >= NLOOP) return;

  // ---- desc path (window i = b), hidden under the copy drain ----
  const int i = b;
  const uint32_t K1 = (uint32_t)seedp[0];

  __shared__ uint32_t rb[CC * 64];
  __shared__ unsigned char mlist[64];
  __shared__ unsigned char srcbuf[CC][64];

  uint32_t k0, k1, a0, a1;
  tf2x32(0u, K1, 0u, (uint32_t)i, k0, k1);

  uint32_t kh0,kh1,kw0,kw1,kp0,kp1,kq0,kq1,kr0,kr1;
  tf2x32(k0,k1,0u,0u,kh0,kh1);   // kh
  tf2x32(k0,k1,0u,1u,kw0,kw1);   // kw
  tf2x32(k0,k1,0u,2u,kp0,kp1);   // kph
  tf2x32(k0,k1,0u,3u,kq0,kq1);   // kpw
  tf2x32(k0,k1,0u,4u,kr0,kr1);   // kperm

  // 192 uniform draws for kperm, one per thread 0..191
  if (tid < CC * 64) rb[tid] = rb32(kr0, kr1, 0u, (uint32_t)tid) >> 9;

  tf2x32(kh0,kh1,0u,1u,a0,a1);   // randint internal split -> k2
  const int wsh = 1 + (int)(rb32(a0,a1,0u,0u) & 7u);
  tf2x32(kw0,kw1,0u,1u,a0,a1);
  const int wsw = 1 + (int)(rb32(a0,a1,0u,0u) & 7u);

  const float uh = __uint_as_float(0x3F800000u | (rb32(kp0,kp1,0u,0u) >> 9)) - 1.0f;
  const float uw = __uint_as_float(0x3F800000u | (rb32(kq0,kq1,0u,0u) >> 9)) - 1.0f;

  const int ph = (int)(uh * (float)(HH - wsh + 1));
  const int pw = (int)(uw * (float)(WW - wsw + 1));
  const int psh = min(ph, HH - 8);
  const int psw = min(pw, WW - 8);
  const int offh = ph - psh;
  const int offw = pw - psw;

  const uint32_t colm = ((1u << wsw) - 1u) << offw;
  unsigned long long rows = (wsh == 8) ? ~0ull : ((1ull << (8 * wsh)) - 1ull);
  rows <<= (8 * offh);
  const unsigned long long mask =
      rows & (0x0101010101010101ull * (unsigned long long)colm);

  if (tid < 64) {
    srcbuf[0][tid] = (unsigned char)tid;
    srcbuf[1][tid] = (unsigned char)tid;
    srcbuf[2][tid] = (unsigned char)tid;
    const int ordinal =
        __popcll(mask & ((tid == 0) ? 0ull : ((1ull << tid) - 1ull)));
    if ((mask >> tid) & 1ull) mlist[ordinal] = (unsigned char)tid;
  }
  if (tid == 0) geo[i] = make_int4(ph, pw, wsh, wsw);
  __syncthreads();   // rb, mlist, identity srcbuf ready

  // stable argsort rank -> permutation (dest mlist[rank] <- src q)
  if (tid < CC * 64) {
    const int c = tid >> 6, q = tid & 63;
    if ((mask >> q) & 1ull) {
      const uint32_t myk = rb[(c << 6) | q];
      int rank = 0;
      for (int q2 = 0; q2 < 64; ++q2) {
        if ((mask >> q2) & 1ull) {
          const uint32_t k2 = rb[(c << 6) | q2];
          if (k2 < myk || (k2 == myk && q2 < q)) ++rank;
        }
      }
      srcbuf[c][mlist[rank]] = (unsigned char)q;
    }
  }
  __syncthreads();

  if (tid < CC * 64) {
    const int c = tid >> 6, q = tid & 63;
    d[i].src[c][q] = srcbuf[c][q];
  }
  if (tid == 0) {
    d[i].psh = psh; d[i].psw = psw; d[i].mask = mask;
  }
}

// Dispatch 2: live_i = mask_i minus coverage by later windows (dense 16B
// geometry reads, L2-hot), then scatter window i from the ORIGINAL image.
__global__ __launch_bounds__(NTHR) void k_live_apply(
    const float* __restrict__ in, float* __restrict__ out,
    const Desc* __restrict__ d, const int4* __restrict__ geo) {
  const int i = blockIdx.x;
  const int t = threadIdx.x;   // 256
  const int psh = d[i].psh, psw = d[i].psw;
  unsigned long long clr = 0ull;
  for (int j = i + 1 + t; j < NLOOP; j += NTHR) {
    const int4 g = geo[j];          // {ph, pw, wsh, wsw}
    const int r0 = max(0, g.x - psh), r1 = min(8, g.x + g.z - psh);
    const int c0 = max(0, g.y - psw), c1 = min(8, g.y + g.w - psw);
    if (r0 < r1 && c0 < c1) {
      const uint32_t cm = ((1u << (c1 - c0)) - 1u) << c0;
      const int nr = r1 - r0;
      unsigned long long rr = (nr == 8) ? ~0ull : ((1ull << (8 * nr)) - 1ull);
      rr <<= (8 * r0);
      clr |= rr & (0x0101010101010101ull * (unsigned long long)cm);
    }
  }
  // wave-level OR-reduce (no barriers), then one barrier for 4 wave results
  #pragma unroll
  for (int m = 32; m > 0; m >>= 1) clr |= __shfl_xor(clr, m, 64);
  __shared__ unsigned long long sh[4];
  if ((t & 63) == 0) sh[t >> 6] = clr;
  __syncthreads();
  const unsigned long long live =
      d[i].mask & ~(sh[0] | sh[1] | sh[2] | sh[3]);

  // scatter: one thread per (c, q); sources always from the ORIGINAL image
  if (t < CC * 64) {
    const int c = t >> 6, q = t & 63;
    if ((live >> q) & 1ull) {
      const int s = d[i].src[c][q];
      const size_t base = (size_t)c * (size_t)HH * (size_t)WW;
      out[base + (size_t)(psh + (q >> 3)) * WW + (size_t)(psw + (q & 7))] =
          in[base + (size_t)(psh + (s >> 3)) * WW + (size_t)(psw + (s & 7))];
    }
  }
}

extern "C" void kernel_launch(void* const* d_in, const int* in_sizes, int n_in,
                              void* d_out, int out_size, void* d_ws, size_t ws_size,
                              hipStream_t stream) {
  const float* img = (const float*)d_in[0];
  const int* seed = (const int*)d_in[1];
  float* out = (float*)d_out;
  Desc* d = (Desc*)d_ws;                                     // 256,000 B
  int4* geo = (int4*)((char*)d_ws + NLOOP * sizeof(Desc));   // +16,000 B

  hipLaunchKernelGGL(k_copy_desc, dim3(NBLK), dim3(NTHR), 0, stream,
                     seed, d, geo, img, out);
  hipLaunchKernelGGL(k_live_apply, dim3(NLOOP), dim3(NTHR), 0, stream,
                     img, out, d, geo);
}